// Round 15
// baseline (240.157 us; speedup 1.0000x reference)
//
#include <hip/hip_runtime.h>
#include <hip/hip_bf16.h>
#include <stdint.h>

typedef __attribute__((ext_vector_type(8)))  __bf16 bf16x8;
typedef __attribute__((ext_vector_type(4)))  float  f32x4;
typedef __attribute__((ext_vector_type(16))) float  f32x16;
typedef __hip_bfloat16 bf16_t;

#define T_SEQ 2048
#define D_MODEL 1024
#define N_HEADS 16
#define N_KV 4
#define HD 64
#define LDQKV 1536
#define KDIM 1024

// Convert 16 consecutive fp32 (4x float4) -> 16 bf16 (2x int4)
__device__ inline void cvt16(const float4* __restrict__ g, int4* __restrict__ s) {
  float4 v0 = g[0], v1 = g[1], v2 = g[2], v3 = g[3];
  union { int4 i[2]; __hip_bfloat162 h[8]; } u;
  u.h[0] = __float22bfloat162_rn(make_float2(v0.x, v0.y));
  u.h[1] = __float22bfloat162_rn(make_float2(v0.z, v0.w));
  u.h[2] = __float22bfloat162_rn(make_float2(v1.x, v1.y));
  u.h[3] = __float22bfloat162_rn(make_float2(v1.z, v1.w));
  u.h[4] = __float22bfloat162_rn(make_float2(v2.x, v2.y));
  u.h[5] = __float22bfloat162_rn(make_float2(v2.z, v2.w));
  u.h[6] = __float22bfloat162_rn(make_float2(v3.x, v3.y));
  u.h[7] = __float22bfloat162_rn(make_float2(v3.z, v3.w));
  s[0] = u.i[0]; s[1] = u.i[1];
}

__device__ inline void storeC(bf16_t* p, float v) { *p = __float2bfloat16(v); }
__device__ inline void storeC(float* p, float v) { *p = v; }

// v_permlane32_swap_b32 vdst, vsrc: after plswap(a,b): a={a_L,b_L}, b={a_U,b_U}
__device__ inline void plswap(unsigned& a, unsigned& b) {
  asm volatile("v_permlane32_swap_b32 %0, %1" : "+v"(a), "+v"(b));
}

// HW transcendental exp2 (input already in log2 domain)
__device__ inline float fexp2(float x) {
  float r; asm("v_exp_f32 %0, %1" : "=v"(r) : "v"(x)); return r;
}
// HW packed fp32->bf16 (T12 recipe; no builtin on gfx950)
__device__ inline unsigned cvtpk(float lo, float hi) {
  unsigned r; asm("v_cvt_pk_bf16_f32 %0, %1, %2" : "=v"(r) : "v"(lo), "v"(hi));
  return r;
}

// async global->LDS, 16B per lane; lds dest must be wave-uniform base.
__device__ inline void gll16(const bf16_t* g, bf16_t* l) {
  __builtin_amdgcn_global_load_lds(
      (const __attribute__((address_space(1))) void*)g,
      (__attribute__((address_space(3))) void*)l, 16, 0, 0);
}

// ---------------------------------------------------------------------------
// fp32 -> bf16 bulk converts
// ---------------------------------------------------------------------------
__global__ __launch_bounds__(256) void to_bf16(const float* __restrict__ s,
                                               bf16_t* __restrict__ d,
                                               const int n16) {
  const int i = blockIdx.x * 256 + threadIdx.x;
  if (i < n16) cvt16((const float4*)s + i * 4, (int4*)d + i * 2);
}

// all weights in one launch: [0,64K) Wq->wqkvb, [64K,80K) Wk, [80K,96K) Wv,
// [96K,160K) Wo->wob   (units of 16 elements)
__global__ __launch_bounds__(256) void w_cvt(
    const float* __restrict__ Wq, const float* __restrict__ Wk,
    const float* __restrict__ Wv, const float* __restrict__ Wo,
    bf16_t* __restrict__ wqkvb, bf16_t* __restrict__ wob) {
  const int i = blockIdx.x * 256 + threadIdx.x;
  const float* s; bf16_t* d; int off;
  if (i < 65536)       { s = Wq; d = wqkvb;                off = i; }
  else if (i < 81920)  { s = Wk; d = wqkvb + 1024 * 1024;  off = i - 65536; }
  else if (i < 98304)  { s = Wv; d = wqkvb + 1280 * 1024;  off = i - 81920; }
  else                 { s = Wo; d = wob;                  off = i - 98304; }
  cvt16((const float4*)s + off * 4, (int4*)d + off * 2);
}

// ---------------------------------------------------------------------------
// GEMM bf16 x bf16 (unchanged from round 14 — passing, fused QKV epilogue)
// ---------------------------------------------------------------------------
template <int MODE, typename CT>
__global__ __launch_bounds__(256) void gemm_bb(
    const bf16_t* __restrict__ A, const bf16_t* __restrict__ W,
    CT* __restrict__ C, const int ldC,
    const float* __restrict__ cosb, const float* __restrict__ sinb,
    const float* __restrict__ qs, const float* __restrict__ ks,
    bf16_t* __restrict__ v_t)
{
  __shared__ bf16_t As[128 * 32];
  __shared__ bf16_t Bs[128 * 32];
  const int tid = threadIdx.x;
  const int lane = tid & 63;
  const int wv = tid >> 6;
  const int wr = wv >> 1, wc = wv & 1;
  const int m0 = blockIdx.y * 128;
  const int n0 = blockIdx.x * 128;

  const int srow = lane >> 2;
  const int scol = (lane & 3) * 8;
  const bf16_t* gA = A + (size_t)(m0 + 32 * wv + srow) * KDIM + scol;
  const bf16_t* gB = W + (size_t)(n0 + 32 * wv + srow) * KDIM + scol;
  bf16_t* lA = As + wv * 1024;
  bf16_t* lB = Bs + wv * 1024;

  f32x4 acc[4][4];
#pragma unroll
  for (int m = 0; m < 4; ++m)
#pragma unroll
    for (int n = 0; n < 4; ++n)
      acc[m][n] = {0.f, 0.f, 0.f, 0.f};

  const int fr = lane & 15;
  const int fq = lane >> 4;

  for (int k0 = 0; k0 < KDIM; k0 += 32) {
    gll16(gA + k0, lA);
    gll16(gA + 16 * KDIM + k0, lA + 512);
    gll16(gB + k0, lB);
    gll16(gB + 16 * KDIM + k0, lB + 512);
    __syncthreads();
    bf16x8 af[4], bfv[4];
#pragma unroll
    for (int m = 0; m < 4; ++m)
      af[m] = *(const bf16x8*)(&As[(wr * 64 + m * 16 + fr) * 32 + fq * 8]);
#pragma unroll
    for (int n = 0; n < 4; ++n)
      bfv[n] = *(const bf16x8*)(&Bs[(wc * 64 + n * 16 + fr) * 32 + fq * 8]);
#pragma unroll
    for (int m = 0; m < 4; ++m)
#pragma unroll
      for (int n = 0; n < 4; ++n)
        acc[m][n] = __builtin_amdgcn_mfma_f32_16x16x32_bf16(af[m], bfv[n],
                                                            acc[m][n], 0, 0, 0);
    __syncthreads();
  }

  if (MODE == 0 || n0 < 1280) {
    if (MODE == 1) {
      const float* stab = (n0 < 1024) ? qs : ks;
      float sc0 = stab[fr], sc1 = stab[16 + fr], sc2 = stab[32 + fr], sc3 = stab[48 + fr];
#pragma unroll
      for (int m = 0; m < 4; ++m)
#pragma unroll
        for (int r = 0; r < 4; ++r) {
          const int row = m0 + wr * 64 + m * 16 + fq * 4 + r;
          const int t = row & (T_SEQ - 1);
          float ss = acc[m][0][r] * acc[m][0][r] + acc[m][1][r] * acc[m][1][r]
                   + acc[m][2][r] * acc[m][2][r] + acc[m][3][r] * acc[m][3][r];
          ss += __shfl_xor(ss, 1);
          ss += __shfl_xor(ss, 2);
          ss += __shfl_xor(ss, 4);
          ss += __shfl_xor(ss, 8);
          const float nrm = rsqrtf(ss * (1.f / 64.f) + 1e-6f);
          const float v0 = acc[m][0][r] * nrm * sc0;
          const float v1 = acc[m][1][r] * nrm * sc1;
          const float v2 = acc[m][2][r] * nrm * sc2;
          const float v3 = acc[m][3][r] * nrm * sc3;
          const float c = cosb[t * 16 + fr];
          const float s = sinb[t * 16 + fr];
          const float r0 = v0 * c - v1 * s;
          const float r1 = v0 * s + v1 * c;
          bf16_t* p = (bf16_t*)C + (size_t)row * ldC + n0 + wc * 64 + fr;
          p[0]  = __float2bfloat16(r0);
          p[16] = __float2bfloat16(r1);
          p[32] = __float2bfloat16(v2);
          p[48] = __float2bfloat16(v3);
        }
    } else {
#pragma unroll
      for (int m = 0; m < 4; ++m)
#pragma unroll
        for (int n = 0; n < 4; ++n)
#pragma unroll
          for (int r = 0; r < 4; ++r) {
            const int row = wr * 64 + m * 16 + fq * 4 + r;
            const int col = wc * 64 + n * 16 + fr;
            storeC(&C[(size_t)(m0 + row) * ldC + n0 + col], acc[m][n][r]);
          }
    }
  } else {
#pragma unroll
    for (int m = 0; m < 4; ++m) {
      const int row0 = m0 + wr * 64 + m * 16 + fq * 4;
      const int b = row0 >> 11, t0 = row0 & (T_SEQ - 1);
#pragma unroll
      for (int n = 0; n < 4; ++n) {
        const int vcol = n0 - 1280 + wc * 64 + n * 16 + fr;
        const int g = b * 4 + (vcol >> 6);
        const int d = vcol & 63;
        uint2 pk2;
        pk2.x = cvtpk(acc[m][n][0], acc[m][n][1]);
        pk2.y = cvtpk(acc[m][n][2], acc[m][n][3]);
        *(uint2*)(v_t + ((size_t)g * HD + d) * T_SEQ + t0) = pk2;
      }
    }
  }
}

// ---------------------------------------------------------------------------
// Causal GQA flash attention v11 — uniform 2-wave blocks, paired strips.
// Block = 2 waves; wave wv handles strip s=2p+wv (pass 0) then 63-s (pass 1)
// => every wave 65 tiles, every block 66 staging rounds: perfectly uniform,
// no tail, no balance permutation. Grid 2048 = 8 blocks/CU = 16 waves/CU
// co-resident (LDS 16KB/block). Per-tile math identical to v10 (passing).
// LDS map (int4): buf*512 + [K: kr*8 + (kslot^(kr&7))]
//                 buf*512 + 256 + [V: vd*4 + (vslot^((vd>>1)&3))]
// ---------------------------------------------------------------------------
__global__ __launch_bounds__(128) void attn(
    const bf16_t* __restrict__ qkv, const bf16_t* __restrict__ v_t,
    bf16_t* __restrict__ y)
{
  __shared__ int4 lds[1024];      // 16 KB: dbuf x (K 4KB + V 4KB)
  const int tid  = threadIdx.x;   // 0..127
  const int lane = tid & 63;
  const int wv   = tid >> 6;      // 0,1
  const int ql   = lane & 31;
  const int hi   = lane >> 5;
  const int id   = (int)blockIdx.x;          // 0..2047
  const int low3 = id & 7;
  const int rest = id >> 3;                  // 0..255
  const int gsel = rest & 1;
  const int hh   = (rest >> 1) & 3;
  const int p    = rest >> 3;                // 0..31
  const int g16  = low3 + 8 * gsel;          // b*4+kvh (same-XCD clustering)
  const int b    = g16 >> 2, kvh = g16 & 3;
  const int h    = kvh * 4 + hh;
  const int sA   = 2 * p + wv;               // pass-0 strip; pass-1 = 63-sA
  const float SCALE_LOG2 = 0.125f * 1.44269504089f;

  // --- staging: 128 threads cover 256 K-slots + 256 V-slots (2+2 each) ---
  const int ks1 = tid + 128;
  const int kr0 = tid >> 3, kc0 = tid & 7;
  const int kr1 = ks1 >> 3, kc1 = ks1 & 7;
  const bf16_t* gK0 = qkv + (size_t)(b * T_SEQ + kr0) * LDQKV + 1024 + kvh * HD + kc0 * 8;
  const bf16_t* gK1 = qkv + (size_t)(b * T_SEQ + kr1) * LDQKV + 1024 + kvh * HD + kc1 * 8;
  const int wK0 = kr0 * 8 + (kc0 ^ (kr0 & 7));
  const int wK1 = kr1 * 8 + (kc1 ^ (kr1 & 7));
  const int vd0 = tid >> 2, vc0 = tid & 3;
  const int vs1 = tid + 128;
  const int vd1 = vs1 >> 2, vc1 = vs1 & 3;
  const bf16_t* gV0 = v_t + (size_t)((b * N_KV + kvh) * HD + vd0) * T_SEQ + vc0 * 8;
  const bf16_t* gV1 = v_t + (size_t)((b * N_KV + kvh) * HD + vd1) * T_SEQ + vc1 * 8;
  const int wV0 = 256 + vd0 * 4 + (vc0 ^ ((vd0 >> 1) & 3));
  const int wV1 = 256 + vd1 * 4 + (vc1 ^ ((vd1 >> 1) & 3));

  // --- fragment read indices (wave-local, + buf*512) ---
  int kridx[4];
#pragma unroll
  for (int c = 0; c < 4; ++c)
    kridx[c] = ql * 8 + ((2 * c + hi) ^ (ql & 7));
  const int vsw = (ql >> 1) & 3;
  const int v0idx = 256 + ql * 4 + (hi ^ vsw);
  const int v1idx = 256 + ql * 4 + ((2 + hi) ^ vsw);
  const int v2idx = 256 + (ql + 32) * 4 + (hi ^ vsw);
  const int v3idx = 256 + (ql + 32) * 4 + ((2 + hi) ^ vsw);

  union ob { unsigned u[4]; bf16x8 v; } onesf;
#pragma unroll
  for (int i = 0; i < 4; ++i) onesf.u[i] = 0x3F803F80u;

  f32x16 zro;
#pragma unroll
  for (int i = 0; i < 16; ++i) zro[i] = 0.f;

  int buf = 0;
#pragma unroll
  for (int pi = 0; pi < 2; ++pi) {
    const int s = pi ? (63 - sA) : sA;
    const int q_glob = s * 32 + ql;
    const int nt = s + 1;                             // this wave's tiles
    const int ntmax = pi ? (64 - 2 * p) : (2 * p + 2); // block-uniform

    // Q fragments, pre-scaled into log2 domain
    const bf16_t* Qrow = qkv + (size_t)(b * T_SEQ + q_glob) * LDQKV + h * HD + hi * 8;
    bf16x8 qfrag[4];
#pragma unroll
    for (int c = 0; c < 4; ++c) {
      bf16x8 raw = *(const bf16x8*)(Qrow + c * 16);
      bf16x8 sc;
#pragma unroll
      for (int j = 0; j < 8; ++j)
        sc[j] = (__bf16)((float)raw[j] * SCALE_LOG2);
      qfrag[c] = sc;
    }

    f32x16 acc0, acc1, accL;
#pragma unroll
    for (int i = 0; i < 16; ++i) { acc0[i] = 0.f; acc1[i] = 0.f; accL[i] = 0.f; }
    float m_run = -1e30f;

    // prologue: stage tile 0 into current buf
    {
      int4 a0 = *(const int4*)gK0; int4 a1 = *(const int4*)gK1;
      int4 a2 = *(const int4*)gV0; int4 a3 = *(const int4*)gV1;
      const int nb = buf * 512;
      lds[nb + wK0] = a0; lds[nb + wK1] = a1;
      lds[nb + wV0] = a2; lds[nb + wV1] = a3;
    }
    __syncthreads();

    const bf16_t* pK0 = gK0 + (size_t)32 * LDQKV;
    const bf16_t* pK1 = gK1 + (size_t)32 * LDQKV;
    const bf16_t* pV0 = gV0 + 32;
    const bf16_t* pV1 = gV1 + 32;

    for (int t = 0; t < ntmax; ++t) {
      int4 a0, a1, a2, a3;
      const bool more = (t + 1 < ntmax);
      if (more) {
        a0 = *(const int4*)pK0; a1 = *(const int4*)pK1;
        a2 = *(const int4*)pV0; a3 = *(const int4*)pV1;
      }

      if (t < nt) {
        const int k0 = t << 5;
        const bool masked = (t == nt - 1);
        const int base = buf * 512;

        bf16x8 kf0 = *(const bf16x8*)&lds[base + kridx[0]];
        bf16x8 kf1 = *(const bf16x8*)&lds[base + kridx[1]];
        bf16x8 kf2 = *(const bf16x8*)&lds[base + kridx[2]];
        bf16x8 kf3 = *(const bf16x8*)&lds[base + kridx[3]];

        f32x16 st = __builtin_amdgcn_mfma_f32_32x32x16_bf16(kf0, qfrag[0], zro, 0, 0, 0);
        st = __builtin_amdgcn_mfma_f32_32x32x16_bf16(kf1, qfrag[1], st, 0, 0, 0);
        st = __builtin_amdgcn_mfma_f32_32x32x16_bf16(kf2, qfrag[2], st, 0, 0, 0);
        st = __builtin_amdgcn_mfma_f32_32x32x16_bf16(kf3, qfrag[3], st, 0, 0, 0);

        if (masked) {
#pragma unroll
          for (int rr = 0; rr < 16; ++rr) {
            const int kg = k0 + (rr & 3) + 8 * (rr >> 2) + 4 * hi;
            if (kg > q_glob) st[rr] = -1e30f;
          }
        }
        float m01 = fmaxf(fmaxf(st[0], st[1]), st[2]);
        float m02 = fmaxf(fmaxf(st[3], st[4]), st[5]);
        float m03 = fmaxf(fmaxf(st[6], st[7]), st[8]);
        float m04 = fmaxf(fmaxf(st[9], st[10]), st[11]);
        float m05 = fmaxf(fmaxf(st[12], st[13]), st[14]);
        float m06 = fmaxf(fmaxf(m01, m02), m03);
        float m07 = fmaxf(fmaxf(m04, m05), st[15]);
        const float bmax = fmaxf(m06, m07);
        if (__any(bmax > m_run + 8.f)) {        // T13 defer-max
          const float rmax = fmaxf(bmax, __shfl_xor(bmax, 32));
          const float mnew = fmaxf(m_run, rmax);
          const float corr = fexp2(m_run - mnew);
#pragma unroll
          for (int i = 0; i < 16; ++i) { acc0[i] *= corr; acc1[i] *= corr; }
          accL[0] *= corr;
          m_run = mnew;
        }
        float pp[16];
#pragma unroll
        for (int rr = 0; rr < 16; ++rr) pp[rr] = fexp2(st[rr] - m_run);

        unsigned w[8];
#pragma unroll
        for (int i = 0; i < 8; ++i) w[i] = cvtpk(pp[2 * i], pp[2 * i + 1]);
        plswap(w[0], w[2]); plswap(w[1], w[3]);
        plswap(w[4], w[6]); plswap(w[5], w[7]);
        union fu { unsigned u[4]; bf16x8 v; };
        fu f1, f2;
        f1.u[0] = w[0]; f1.u[1] = w[1]; f1.u[2] = w[2]; f1.u[3] = w[3];
        f2.u[0] = w[4]; f2.u[1] = w[5]; f2.u[2] = w[6]; f2.u[3] = w[7];

        bf16x8 vf0 = *(const bf16x8*)&lds[base + v0idx];
        bf16x8 vf1 = *(const bf16x8*)&lds[base + v1idx];
        bf16x8 vf2 = *(const bf16x8*)&lds[base + v2idx];
        bf16x8 vf3 = *(const bf16x8*)&lds[base + v3idx];

        acc0 = __builtin_amdgcn_mfma_f32_32x32x16_bf16(vf0, f1.v, acc0, 0, 0, 0);
        acc0 = __builtin_amdgcn_mfma_f32_32x32x16_bf16(vf1, f2.v, acc0, 0, 0, 0);
        acc1 = __builtin_amdgcn_mfma_f32_32x32x16_bf16(vf2, f1.v, acc1, 0, 0, 0);
        acc1 = __builtin_amdgcn_mfma_f32_32x32x16_bf16(vf3, f2.v, acc1, 0, 0, 0);
        accL = __builtin_amdgcn_mfma_f32_32x32x16_bf16(onesf.v, f1.v, accL, 0, 0, 0);
        accL = __builtin_amdgcn_mfma_f32_32x32x16_bf16(onesf.v, f2.v, accL, 0, 0, 0);
      }

      if (more) {
        const int nb = (buf ^ 1) * 512;
        lds[nb + wK0] = a0; lds[nb + wK1] = a1;
        lds[nb + wV0] = a2; lds[nb + wV1] = a3;
        pK0 += (size_t)32 * LDQKV; pK1 += (size_t)32 * LDQKV;
        pV0 += 32; pV1 += 32;
      }
      __syncthreads();
      buf ^= 1;
    }

    // epilogue: O = acc / l  (l = accL[0], identical across half-lanes)
    const float inv = 1.f / accL[0];
    bf16_t* yrow = y + (size_t)(b * T_SEQ + q_glob) * D_MODEL + h * HD;
#pragma unroll
    for (int gg = 0; gg < 4; ++gg) {
      uint2 o0, o1;
      o0.x = cvtpk(acc0[4 * gg + 0] * inv, acc0[4 * gg + 1] * inv);
      o0.y = cvtpk(acc0[4 * gg + 2] * inv, acc0[4 * gg + 3] * inv);
      o1.x = cvtpk(acc1[4 * gg + 0] * inv, acc1[4 * gg + 1] * inv);
      o1.y = cvtpk(acc1[4 * gg + 2] * inv, acc1[4 * gg + 3] * inv);
      *(uint2*)(yrow + 8 * gg + 4 * hi)      = o0;
      *(uint2*)(yrow + 32 + 8 * gg + 4 * hi) = o1;
    }
  }
}

// ---------------------------------------------------------------------------
extern "C" void kernel_launch(void* const* d_in, const int* in_sizes, int n_in,
                              void* d_out, int out_size, void* d_ws,
                              size_t ws_size, hipStream_t stream) {
  const float* x    = (const float*)d_in[0];
  const float* cosb = (const float*)d_in[1];
  const float* sinb = (const float*)d_in[2];
  const float* Wq   = (const float*)d_in[3];
  const float* Wk   = (const float*)d_in[4];
  const float* Wv   = (const float*)d_in[5];
  const float* Wo   = (const float*)d_in[6];
  const float* qs   = (const float*)d_in[7];
  const float* ks   = (const float*)d_in[8];
  float* out = (float*)d_out;   // reference output dtype is float32

  char* ws = (char*)d_ws;
  bf16_t* qkv   = (bf16_t*)ws;                       // 25165824 B
  bf16_t* v_t   = (bf16_t*)(ws + 25165824);          // 4194304 B
  bf16_t* y     = (bf16_t*)(ws + 29360128);          // 16777216 B (= xb alias)
  bf16_t* xb    = y;                                 // xb dead before attn writes y
  bf16_t* wqkvb = (bf16_t*)(ws + 46137344);          // 3145728 B
  bf16_t* wob   = (bf16_t*)(ws + 49283072);          // 2097152 B

  // 0. fp32 -> bf16 converts
  to_bf16<<<dim3(2048), 256, 0, stream>>>(x, xb, 524288);
  w_cvt<<<dim3(640), 256, 0, stream>>>(Wq, Wk, Wv, Wo, wqkvb, wob);

  // 1. fused QKV projection + RMSNorm + RoPE + V-transpose
  gemm_bb<1, bf16_t><<<dim3(12, 64), 256, 0, stream>>>(
      xb, wqkvb, qkv, LDQKV, cosb, sinb, qs, ks, v_t);
  // 2. causal GQA flash attention -> y  (uniform 2-wave blocks)
  attn<<<dim3(2048), 128, 0, stream>>>(qkv, v_t, y);
  // 3. output projection
  gemm_bb<0, float><<<dim3(8, 64), 256, 0, stream>>>(
      y, wob, out, D_MODEL, nullptr, nullptr, nullptr, nullptr, nullptr);
}

// Round 16
// 163.265 us; speedup vs baseline: 1.4710x; 1.4710x over previous
//
#include <hip/hip_runtime.h>
#include <hip/hip_bf16.h>
#include <stdint.h>

typedef __attribute__((ext_vector_type(8)))  __bf16 bf16x8;
typedef __attribute__((ext_vector_type(4)))  float  f32x4;
typedef __attribute__((ext_vector_type(16))) float  f32x16;
typedef __hip_bfloat16 bf16_t;

#define T_SEQ 2048
#define D_MODEL 1024
#define N_HEADS 16
#define N_KV 4
#define HD 64
#define LDQKV 1536
#define KDIM 1024

// Convert 16 consecutive fp32 (4x float4) -> 16 bf16 (2x int4)
__device__ inline void cvt16(const float4* __restrict__ g, int4* __restrict__ s) {
  float4 v0 = g[0], v1 = g[1], v2 = g[2], v3 = g[3];
  union { int4 i[2]; __hip_bfloat162 h[8]; } u;
  u.h[0] = __float22bfloat162_rn(make_float2(v0.x, v0.y));
  u.h[1] = __float22bfloat162_rn(make_float2(v0.z, v0.w));
  u.h[2] = __float22bfloat162_rn(make_float2(v1.x, v1.y));
  u.h[3] = __float22bfloat162_rn(make_float2(v1.z, v1.w));
  u.h[4] = __float22bfloat162_rn(make_float2(v2.x, v2.y));
  u.h[5] = __float22bfloat162_rn(make_float2(v2.z, v2.w));
  u.h[6] = __float22bfloat162_rn(make_float2(v3.x, v3.y));
  u.h[7] = __float22bfloat162_rn(make_float2(v3.z, v3.w));
  s[0] = u.i[0]; s[1] = u.i[1];
}

__device__ inline void storeC(bf16_t* p, float v) { *p = __float2bfloat16(v); }
__device__ inline void storeC(float* p, float v) { *p = v; }

// v_permlane32_swap_b32 vdst, vsrc: after plswap(a,b): a={a_L,b_L}, b={a_U,b_U}
__device__ inline void plswap(unsigned& a, unsigned& b) {
  asm volatile("v_permlane32_swap_b32 %0, %1" : "+v"(a), "+v"(b));
}

// HW transcendental exp2 (input already in log2 domain)
__device__ inline float fexp2(float x) {
  float r; asm("v_exp_f32 %0, %1" : "=v"(r) : "v"(x)); return r;
}
// HW packed fp32->bf16 (T12 recipe; no builtin on gfx950)
__device__ inline unsigned cvtpk(float lo, float hi) {
  unsigned r; asm("v_cvt_pk_bf16_f32 %0, %1, %2" : "=v"(r) : "v"(lo), "v"(hi));
  return r;
}

// async global->LDS, 16B per lane; lds dest must be wave-uniform base.
__device__ inline void gll16(const bf16_t* g, bf16_t* l) {
  __builtin_amdgcn_global_load_lds(
      (const __attribute__((address_space(1))) void*)g,
      (__attribute__((address_space(3))) void*)l, 16, 0, 0);
}

// ---------------------------------------------------------------------------
// fp32 -> bf16 bulk convert, x + all weights in ONE launch (units of 16 elem):
// [0,512K) x -> xb; [512K,576K) Wq; [576K,592K) Wk; [592K,608K) Wv;
// [608K,672K) Wo.
// ---------------------------------------------------------------------------
__global__ __launch_bounds__(256) void all_cvt(
    const float* __restrict__ x,
    const float* __restrict__ Wq, const float* __restrict__ Wk,
    const float* __restrict__ Wv, const float* __restrict__ Wo,
    bf16_t* __restrict__ xb, bf16_t* __restrict__ wqkvb,
    bf16_t* __restrict__ wob) {
  const int i = blockIdx.x * 256 + threadIdx.x;
  const float* s; bf16_t* d; int off;
  if (i < 524288)      { s = x;  d = xb;                   off = i; }
  else if (i < 589824) { s = Wq; d = wqkvb;                off = i - 524288; }
  else if (i < 606208) { s = Wk; d = wqkvb + 1024 * 1024;  off = i - 589824; }
  else if (i < 622592) { s = Wv; d = wqkvb + 1280 * 1024;  off = i - 606208; }
  else                 { s = Wo; d = wob;                  off = i - 622592; }
  cvt16((const float4*)s + off * 4, (int4*)d + off * 2);
}

// ---------------------------------------------------------------------------
// GEMM bf16 x bf16 (unchanged from round 14 — passing, fused QKV epilogue)
// ---------------------------------------------------------------------------
template <int MODE, typename CT>
__global__ __launch_bounds__(256) void gemm_bb(
    const bf16_t* __restrict__ A, const bf16_t* __restrict__ W,
    CT* __restrict__ C, const int ldC,
    const float* __restrict__ cosb, const float* __restrict__ sinb,
    const float* __restrict__ qs, const float* __restrict__ ks,
    bf16_t* __restrict__ v_t)
{
  __shared__ bf16_t As[128 * 32];
  __shared__ bf16_t Bs[128 * 32];
  const int tid = threadIdx.x;
  const int lane = tid & 63;
  const int wv = tid >> 6;
  const int wr = wv >> 1, wc = wv & 1;
  const int m0 = blockIdx.y * 128;
  const int n0 = blockIdx.x * 128;

  const int srow = lane >> 2;
  const int scol = (lane & 3) * 8;
  const bf16_t* gA = A + (size_t)(m0 + 32 * wv + srow) * KDIM + scol;
  const bf16_t* gB = W + (size_t)(n0 + 32 * wv + srow) * KDIM + scol;
  bf16_t* lA = As + wv * 1024;
  bf16_t* lB = Bs + wv * 1024;

  f32x4 acc[4][4];
#pragma unroll
  for (int m = 0; m < 4; ++m)
#pragma unroll
    for (int n = 0; n < 4; ++n)
      acc[m][n] = {0.f, 0.f, 0.f, 0.f};

  const int fr = lane & 15;
  const int fq = lane >> 4;

  for (int k0 = 0; k0 < KDIM; k0 += 32) {
    gll16(gA + k0, lA);
    gll16(gA + 16 * KDIM + k0, lA + 512);
    gll16(gB + k0, lB);
    gll16(gB + 16 * KDIM + k0, lB + 512);
    __syncthreads();
    bf16x8 af[4], bfv[4];
#pragma unroll
    for (int m = 0; m < 4; ++m)
      af[m] = *(const bf16x8*)(&As[(wr * 64 + m * 16 + fr) * 32 + fq * 8]);
#pragma unroll
    for (int n = 0; n < 4; ++n)
      bfv[n] = *(const bf16x8*)(&Bs[(wc * 64 + n * 16 + fr) * 32 + fq * 8]);
#pragma unroll
    for (int m = 0; m < 4; ++m)
#pragma unroll
      for (int n = 0; n < 4; ++n)
        acc[m][n] = __builtin_amdgcn_mfma_f32_16x16x32_bf16(af[m], bfv[n],
                                                            acc[m][n], 0, 0, 0);
    __syncthreads();
  }

  if (MODE == 0 || n0 < 1280) {
    if (MODE == 1) {
      const float* stab = (n0 < 1024) ? qs : ks;
      float sc0 = stab[fr], sc1 = stab[16 + fr], sc2 = stab[32 + fr], sc3 = stab[48 + fr];
#pragma unroll
      for (int m = 0; m < 4; ++m)
#pragma unroll
        for (int r = 0; r < 4; ++r) {
          const int row = m0 + wr * 64 + m * 16 + fq * 4 + r;
          const int t = row & (T_SEQ - 1);
          float ss = acc[m][0][r] * acc[m][0][r] + acc[m][1][r] * acc[m][1][r]
                   + acc[m][2][r] * acc[m][2][r] + acc[m][3][r] * acc[m][3][r];
          ss += __shfl_xor(ss, 1);
          ss += __shfl_xor(ss, 2);
          ss += __shfl_xor(ss, 4);
          ss += __shfl_xor(ss, 8);
          const float nrm = rsqrtf(ss * (1.f / 64.f) + 1e-6f);
          const float v0 = acc[m][0][r] * nrm * sc0;
          const float v1 = acc[m][1][r] * nrm * sc1;
          const float v2 = acc[m][2][r] * nrm * sc2;
          const float v3 = acc[m][3][r] * nrm * sc3;
          const float c = cosb[t * 16 + fr];
          const float s = sinb[t * 16 + fr];
          const float r0 = v0 * c - v1 * s;
          const float r1 = v0 * s + v1 * c;
          bf16_t* p = (bf16_t*)C + (size_t)row * ldC + n0 + wc * 64 + fr;
          p[0]  = __float2bfloat16(r0);
          p[16] = __float2bfloat16(r1);
          p[32] = __float2bfloat16(v2);
          p[48] = __float2bfloat16(v3);
        }
    } else {
#pragma unroll
      for (int m = 0; m < 4; ++m)
#pragma unroll
        for (int n = 0; n < 4; ++n)
#pragma unroll
          for (int r = 0; r < 4; ++r) {
            const int row = wr * 64 + m * 16 + fq * 4 + r;
            const int col = wc * 64 + n * 16 + fr;
            storeC(&C[(size_t)(m0 + row) * ldC + n0 + col], acc[m][n][r]);
          }
    }
  } else {
#pragma unroll
    for (int m = 0; m < 4; ++m) {
      const int row0 = m0 + wr * 64 + m * 16 + fq * 4;
      const int b = row0 >> 11, t0 = row0 & (T_SEQ - 1);
#pragma unroll
      for (int n = 0; n < 4; ++n) {
        const int vcol = n0 - 1280 + wc * 64 + n * 16 + fr;
        const int g = b * 4 + (vcol >> 6);
        const int d = vcol & 63;
        uint2 pk2;
        pk2.x = cvtpk(acc[m][n][0], acc[m][n][1]);
        pk2.y = cvtpk(acc[m][n][2], acc[m][n][3]);
        *(uint2*)(v_t + ((size_t)g * HD + d) * T_SEQ + t0) = pk2;
      }
    }
  }
}

// ---------------------------------------------------------------------------
// Causal GQA flash attention v12 — 4-wave blocks + PAIRED strips:
// wave wv handles strip 4p+wv (pass 0) then 63-(4p+wv) (pass 1). Every block
// = exactly 34 KVBLK=64 rounds -> perfectly time-uniform, zero drain.
// Staging amortization preserved (4 waves share each staged tile; 8.5
// tiles/strip as in r13). Grid 512 = 2 blocks/CU = steady 8 waves/CU.
// Per-tile math/swizzles identical to r13 (passing). + s_setprio around MFMA.
// ---------------------------------------------------------------------------
__global__ __launch_bounds__(256) void attn(
    const bf16_t* __restrict__ qkv, const bf16_t* __restrict__ v_t,
    bf16_t* __restrict__ y)
{
  __shared__ int4 lds[2048];      // 32 KB: dbuf x (K 8KB + V 8KB)
  const int tid  = threadIdx.x;
  const int lane = tid & 63;
  const int wv   = tid >> 6;
  const int ql   = lane & 31;
  const int hi   = lane >> 5;
  const int id   = (int)blockIdx.x;          // 0..511
  const int low3 = id & 7;
  const int rest = id >> 3;                  // 0..63
  const int gsel = rest & 1;
  const int hh   = (rest >> 1) & 3;
  const int p    = rest >> 3;                // 0..7
  const int g16  = low3 + 8 * gsel;          // b*4+kvh (same-XCD clustering)
  const int b    = g16 >> 2, kvh = g16 & 3;
  const int h    = kvh * 4 + hh;
  const int sA   = 4 * p + wv;               // pass-0 strip; pass-1 = 63-sA
  const float SCALE_LOG2 = 0.125f * 1.44269504089f;

  // staging addresses (per 32-k subtile)
  const int kr = tid >> 3, kslot = tid & 7;
  const int vd = tid >> 2, vslot = tid & 3;
  const bf16_t* gK = qkv + (size_t)(b * T_SEQ + kr) * LDQKV + 1024 + kvh * HD + kslot * 8;
  const bf16_t* gV = v_t + (size_t)((b * N_KV + kvh) * HD + vd) * T_SEQ + vslot * 8;
  const int wKidx = kr * 8 + (kslot ^ (kr & 7));              // + u*256 + buf*1024
  const int wVidx = 512 + vd * 4 + (vslot ^ ((vd >> 1) & 3)); // + u*256 + buf*1024

  // fragment read indices (per subtile; + u*256 + buf*1024)
  int kridx[4];
#pragma unroll
  for (int c = 0; c < 4; ++c)
    kridx[c] = ql * 8 + ((2 * c + hi) ^ (ql & 7));
  const int vsw = (ql >> 1) & 3;
  const int v0idx = 512 + ql * 4 + (hi ^ vsw);
  const int v1idx = 512 + ql * 4 + ((2 + hi) ^ vsw);
  const int v2idx = 512 + (ql + 32) * 4 + (hi ^ vsw);
  const int v3idx = 512 + (ql + 32) * 4 + ((2 + hi) ^ vsw);

  union ob { unsigned u[4]; bf16x8 v; } onesf;
#pragma unroll
  for (int i = 0; i < 4; ++i) onesf.u[i] = 0x3F803F80u;

  f32x16 zro;
#pragma unroll
  for (int i = 0; i < 16; ++i) zro[i] = 0.f;

  int buf = 0;
#pragma unroll
  for (int pi = 0; pi < 2; ++pi) {
    const int s = pi ? (63 - sA) : sA;
    const int q_glob = s * 32 + ql;
    const int nt = s + 1;                              // this wave's 32-k tiles
    const int nR = pi ? (32 - 2 * p) : (2 * p + 2);    // block-uniform rounds

    // Q fragments, pre-scaled into log2 domain
    const bf16_t* Qrow = qkv + (size_t)(b * T_SEQ + q_glob) * LDQKV + h * HD + hi * 8;
    bf16x8 qfrag[4];
#pragma unroll
    for (int c = 0; c < 4; ++c) {
      bf16x8 raw = *(const bf16x8*)(Qrow + c * 16);
      bf16x8 sc;
#pragma unroll
      for (int j = 0; j < 8; ++j)
        sc[j] = (__bf16)((float)raw[j] * SCALE_LOG2);
      qfrag[c] = sc;
    }

    f32x16 acc0, acc1, accL;
#pragma unroll
    for (int i = 0; i < 16; ++i) { acc0[i] = 0.f; acc1[i] = 0.f; accL[i] = 0.f; }
    float m_run = -1e30f;

    // prologue: stage round-0 pair (subtiles 0,1) into current buf
    // (previous pass's last reads were fenced by its trailing barrier)
    {
      int4 kA = *(const int4*)gK;
      int4 vA = *(const int4*)gV;
      int4 kB = *(const int4*)(gK + (size_t)32 * LDQKV);
      int4 vB = *(const int4*)(gV + 32);
      const int nb = buf * 1024;
      lds[nb + wKidx] = kA;       lds[nb + wVidx] = vA;
      lds[nb + 256 + wKidx] = kB; lds[nb + 256 + wVidx] = vB;
    }
    __syncthreads();

    for (int r = 0; r < nR; ++r) {
      int4 kA, vA, kB, vB;
      const bool more = (r + 1 < nR);
      if (more) {
        const size_t kAdv = (size_t)(r + 1) * 64 * LDQKV;
        const int vAdv = (r + 1) * 64;
        kA = *(const int4*)(gK + kAdv);
        vA = *(const int4*)(gV + vAdv);
        kB = *(const int4*)(gK + kAdv + (size_t)32 * LDQKV);
        vB = *(const int4*)(gV + vAdv + 32);
      }

#pragma unroll
      for (int u = 0; u < 2; ++u) {
        const int t = 2 * r + u;
        if (t < nt) {
          const int k0 = t << 5;
          const bool masked = (t == nt - 1);
          const int base = buf * 1024 + u * 256;

          bf16x8 kf0 = *(const bf16x8*)&lds[base + kridx[0]];
          bf16x8 kf1 = *(const bf16x8*)&lds[base + kridx[1]];
          bf16x8 kf2 = *(const bf16x8*)&lds[base + kridx[2]];
          bf16x8 kf3 = *(const bf16x8*)&lds[base + kridx[3]];

          __builtin_amdgcn_s_setprio(1);
          f32x16 st = __builtin_amdgcn_mfma_f32_32x32x16_bf16(kf0, qfrag[0], zro, 0, 0, 0);
          st = __builtin_amdgcn_mfma_f32_32x32x16_bf16(kf1, qfrag[1], st, 0, 0, 0);
          st = __builtin_amdgcn_mfma_f32_32x32x16_bf16(kf2, qfrag[2], st, 0, 0, 0);
          st = __builtin_amdgcn_mfma_f32_32x32x16_bf16(kf3, qfrag[3], st, 0, 0, 0);
          __builtin_amdgcn_s_setprio(0);

          if (masked) {
#pragma unroll
            for (int rr = 0; rr < 16; ++rr) {
              const int kg = k0 + (rr & 3) + 8 * (rr >> 2) + 4 * hi;
              if (kg > q_glob) st[rr] = -1e30f;
            }
          }
          float m01 = fmaxf(fmaxf(st[0], st[1]), st[2]);
          float m02 = fmaxf(fmaxf(st[3], st[4]), st[5]);
          float m03 = fmaxf(fmaxf(st[6], st[7]), st[8]);
          float m04 = fmaxf(fmaxf(st[9], st[10]), st[11]);
          float m05 = fmaxf(fmaxf(st[12], st[13]), st[14]);
          float m06 = fmaxf(fmaxf(m01, m02), m03);
          float m07 = fmaxf(fmaxf(m04, m05), st[15]);
          const float bmax = fmaxf(m06, m07);
          if (__any(bmax > m_run + 8.f)) {        // T13 defer-max
            const float rmax = fmaxf(bmax, __shfl_xor(bmax, 32));
            const float mnew = fmaxf(m_run, rmax);
            const float corr = fexp2(m_run - mnew);
#pragma unroll
            for (int i = 0; i < 16; ++i) { acc0[i] *= corr; acc1[i] *= corr; }
            accL[0] *= corr;
            m_run = mnew;
          }
          float pp[16];
#pragma unroll
          for (int rr = 0; rr < 16; ++rr) pp[rr] = fexp2(st[rr] - m_run);

          unsigned w[8];
#pragma unroll
          for (int i = 0; i < 8; ++i) w[i] = cvtpk(pp[2 * i], pp[2 * i + 1]);
          plswap(w[0], w[2]); plswap(w[1], w[3]);
          plswap(w[4], w[6]); plswap(w[5], w[7]);
          union fu { unsigned u[4]; bf16x8 v; };
          fu f1, f2;
          f1.u[0] = w[0]; f1.u[1] = w[1]; f1.u[2] = w[2]; f1.u[3] = w[3];
          f2.u[0] = w[4]; f2.u[1] = w[5]; f2.u[2] = w[6]; f2.u[3] = w[7];

          bf16x8 vf0 = *(const bf16x8*)&lds[base + v0idx];
          bf16x8 vf1 = *(const bf16x8*)&lds[base + v1idx];
          bf16x8 vf2 = *(const bf16x8*)&lds[base + v2idx];
          bf16x8 vf3 = *(const bf16x8*)&lds[base + v3idx];

          __builtin_amdgcn_s_setprio(1);
          acc0 = __builtin_amdgcn_mfma_f32_32x32x16_bf16(vf0, f1.v, acc0, 0, 0, 0);
          acc0 = __builtin_amdgcn_mfma_f32_32x32x16_bf16(vf1, f2.v, acc0, 0, 0, 0);
          acc1 = __builtin_amdgcn_mfma_f32_32x32x16_bf16(vf2, f1.v, acc1, 0, 0, 0);
          acc1 = __builtin_amdgcn_mfma_f32_32x32x16_bf16(vf3, f2.v, acc1, 0, 0, 0);
          accL = __builtin_amdgcn_mfma_f32_32x32x16_bf16(onesf.v, f1.v, accL, 0, 0, 0);
          accL = __builtin_amdgcn_mfma_f32_32x32x16_bf16(onesf.v, f2.v, accL, 0, 0, 0);
          __builtin_amdgcn_s_setprio(0);
        }
      }

      if (more) {
        const int nb = (buf ^ 1) * 1024;
        lds[nb + wKidx] = kA;       lds[nb + wVidx] = vA;
        lds[nb + 256 + wKidx] = kB; lds[nb + 256 + wVidx] = vB;
      }
      __syncthreads();
      buf ^= 1;
    }

    // epilogue: O = acc / l  (l = accL[0], identical across half-lanes)
    const float inv = 1.f / accL[0];
    bf16_t* yrow = y + (size_t)(b * T_SEQ + q_glob) * D_MODEL + h * HD;
#pragma unroll
    for (int gg = 0; gg < 4; ++gg) {
      uint2 o0, o1;
      o0.x = cvtpk(acc0[4 * gg + 0] * inv, acc0[4 * gg + 1] * inv);
      o0.y = cvtpk(acc0[4 * gg + 2] * inv, acc0[4 * gg + 3] * inv);
      o1.x = cvtpk(acc1[4 * gg + 0] * inv, acc1[4 * gg + 1] * inv);
      o1.y = cvtpk(acc1[4 * gg + 2] * inv, acc1[4 * gg + 3] * inv);
      *(uint2*)(yrow + 8 * gg + 4 * hi)      = o0;
      *(uint2*)(yrow + 32 + 8 * gg + 4 * hi) = o1;
    }
  }
}

// ---------------------------------------------------------------------------
extern "C" void kernel_launch(void* const* d_in, const int* in_sizes, int n_in,
                              void* d_out, int out_size, void* d_ws,
                              size_t ws_size, hipStream_t stream) {
  const float* x    = (const float*)d_in[0];
  const float* cosb = (const float*)d_in[1];
  const float* sinb = (const float*)d_in[2];
  const float* Wq   = (const float*)d_in[3];
  const float* Wk   = (const float*)d_in[4];
  const float* Wv   = (const float*)d_in[5];
  const float* Wo   = (const float*)d_in[6];
  const float* qs   = (const float*)d_in[7];
  const float* ks   = (const float*)d_in[8];
  float* out = (float*)d_out;   // reference output dtype is float32

  char* ws = (char*)d_ws;
  bf16_t* qkv   = (bf16_t*)ws;                       // 25165824 B
  bf16_t* v_t   = (bf16_t*)(ws + 25165824);          // 4194304 B
  bf16_t* y     = (bf16_t*)(ws + 29360128);          // 16777216 B (= xb alias)
  bf16_t* xb    = y;                                 // xb dead before attn writes y
  bf16_t* wqkvb = (bf16_t*)(ws + 46137344);          // 3145728 B
  bf16_t* wob   = (bf16_t*)(ws + 49283072);          // 2097152 B

  // 0. fp32 -> bf16 converts (one launch: x + all weights)
  all_cvt<<<dim3(2688), 256, 0, stream>>>(x, Wq, Wk, Wv, Wo, xb, wqkvb, wob);

  // 1. fused QKV projection + RMSNorm + RoPE + V-transpose
  gemm_bb<1, bf16_t><<<dim3(12, 64), 256, 0, stream>>>(
      xb, wqkvb, qkv, LDQKV, cosb, sinb, qs, ks, v_t);
  // 2. causal GQA flash attention -> y (uniform 4-wave paired blocks)
  attn<<<dim3(512), 256, 0, stream>>>(qkv, v_t, y);
  // 3. output projection
  gemm_bb<0, float><<<dim3(8, 64), 256, 0, stream>>>(
      y, wob, out, D_MODEL, nullptr, nullptr, nullptr, nullptr, nullptr);
}

// Round 17
// 160.277 us; speedup vs baseline: 1.4984x; 1.0186x over previous
//
#include <hip/hip_runtime.h>
#include <hip/hip_bf16.h>
#include <stdint.h>

typedef __attribute__((ext_vector_type(8)))  __bf16 bf16x8;
typedef __attribute__((ext_vector_type(4)))  float  f32x4;
typedef __attribute__((ext_vector_type(16))) float  f32x16;
typedef __hip_bfloat16 bf16_t;

#define T_SEQ 2048
#define D_MODEL 1024
#define N_HEADS 16
#define N_KV 4
#define HD 64
#define LDQKV 1536
#define KDIM 1024

// Convert 16 consecutive fp32 (4x float4) -> 16 bf16 (2x int4)
__device__ inline void cvt16(const float4* __restrict__ g, int4* __restrict__ s) {
  float4 v0 = g[0], v1 = g[1], v2 = g[2], v3 = g[3];
  union { int4 i[2]; __hip_bfloat162 h[8]; } u;
  u.h[0] = __float22bfloat162_rn(make_float2(v0.x, v0.y));
  u.h[1] = __float22bfloat162_rn(make_float2(v0.z, v0.w));
  u.h[2] = __float22bfloat162_rn(make_float2(v1.x, v1.y));
  u.h[3] = __float22bfloat162_rn(make_float2(v1.z, v1.w));
  u.h[4] = __float22bfloat162_rn(make_float2(v2.x, v2.y));
  u.h[5] = __float22bfloat162_rn(make_float2(v2.z, v2.w));
  u.h[6] = __float22bfloat162_rn(make_float2(v3.x, v3.y));
  u.h[7] = __float22bfloat162_rn(make_float2(v3.z, v3.w));
  s[0] = u.i[0]; s[1] = u.i[1];
}

__device__ inline void storeC(bf16_t* p, float v) { *p = __float2bfloat16(v); }
__device__ inline void storeC(float* p, float v) { *p = v; }

// v_permlane32_swap_b32 vdst, vsrc: after plswap(a,b): a={a_L,b_L}, b={a_U,b_U}
__device__ inline void plswap(unsigned& a, unsigned& b) {
  asm volatile("v_permlane32_swap_b32 %0, %1" : "+v"(a), "+v"(b));
}

// HW transcendental exp2 (input already in log2 domain)
__device__ inline float fexp2(float x) {
  float r; asm("v_exp_f32 %0, %1" : "=v"(r) : "v"(x)); return r;
}
// HW packed fp32->bf16 (T12 recipe; no builtin on gfx950)
__device__ inline unsigned cvtpk(float lo, float hi) {
  unsigned r; asm("v_cvt_pk_bf16_f32 %0, %1, %2" : "=v"(r) : "v"(lo), "v"(hi));
  return r;
}

// async global->LDS, 16B per lane; lds dest must be wave-uniform base.
__device__ inline void gll16(const bf16_t* g, bf16_t* l) {
  __builtin_amdgcn_global_load_lds(
      (const __attribute__((address_space(1))) void*)g,
      (__attribute__((address_space(3))) void*)l, 16, 0, 0);
}

// ---------------------------------------------------------------------------
// fp32 -> bf16 bulk convert, x + all weights in ONE launch (units of 16 elem)
// ---------------------------------------------------------------------------
__global__ __launch_bounds__(256) void all_cvt(
    const float* __restrict__ x,
    const float* __restrict__ Wq, const float* __restrict__ Wk,
    const float* __restrict__ Wv, const float* __restrict__ Wo,
    bf16_t* __restrict__ xb, bf16_t* __restrict__ wqkvb,
    bf16_t* __restrict__ wob) {
  const int i = blockIdx.x * 256 + threadIdx.x;
  const float* s; bf16_t* d; int off;
  if (i < 524288)      { s = x;  d = xb;                   off = i; }
  else if (i < 589824) { s = Wq; d = wqkvb;                off = i - 524288; }
  else if (i < 606208) { s = Wk; d = wqkvb + 1024 * 1024;  off = i - 589824; }
  else if (i < 622592) { s = Wv; d = wqkvb + 1280 * 1024;  off = i - 606208; }
  else                 { s = Wo; d = wob;                  off = i - 622592; }
  cvt16((const float4*)s + off * 4, (int4*)d + off * 2);
}

// ---------------------------------------------------------------------------
// GEMM bf16 x bf16 (unchanged — passing, fused QKV epilogue)
// ---------------------------------------------------------------------------
template <int MODE, typename CT>
__global__ __launch_bounds__(256) void gemm_bb(
    const bf16_t* __restrict__ A, const bf16_t* __restrict__ W,
    CT* __restrict__ C, const int ldC,
    const float* __restrict__ cosb, const float* __restrict__ sinb,
    const float* __restrict__ qs, const float* __restrict__ ks,
    bf16_t* __restrict__ v_t)
{
  __shared__ bf16_t As[128 * 32];
  __shared__ bf16_t Bs[128 * 32];
  const int tid = threadIdx.x;
  const int lane = tid & 63;
  const int wv = tid >> 6;
  const int wr = wv >> 1, wc = wv & 1;
  const int m0 = blockIdx.y * 128;
  const int n0 = blockIdx.x * 128;

  const int srow = lane >> 2;
  const int scol = (lane & 3) * 8;
  const bf16_t* gA = A + (size_t)(m0 + 32 * wv + srow) * KDIM + scol;
  const bf16_t* gB = W + (size_t)(n0 + 32 * wv + srow) * KDIM + scol;
  bf16_t* lA = As + wv * 1024;
  bf16_t* lB = Bs + wv * 1024;

  f32x4 acc[4][4];
#pragma unroll
  for (int m = 0; m < 4; ++m)
#pragma unroll
    for (int n = 0; n < 4; ++n)
      acc[m][n] = {0.f, 0.f, 0.f, 0.f};

  const int fr = lane & 15;
  const int fq = lane >> 4;

  for (int k0 = 0; k0 < KDIM; k0 += 32) {
    gll16(gA + k0, lA);
    gll16(gA + 16 * KDIM + k0, lA + 512);
    gll16(gB + k0, lB);
    gll16(gB + 16 * KDIM + k0, lB + 512);
    __syncthreads();
    bf16x8 af[4], bfv[4];
#pragma unroll
    for (int m = 0; m < 4; ++m)
      af[m] = *(const bf16x8*)(&As[(wr * 64 + m * 16 + fr) * 32 + fq * 8]);
#pragma unroll
    for (int n = 0; n < 4; ++n)
      bfv[n] = *(const bf16x8*)(&Bs[(wc * 64 + n * 16 + fr) * 32 + fq * 8]);
#pragma unroll
    for (int m = 0; m < 4; ++m)
#pragma unroll
      for (int n = 0; n < 4; ++n)
        acc[m][n] = __builtin_amdgcn_mfma_f32_16x16x32_bf16(af[m], bfv[n],
                                                            acc[m][n], 0, 0, 0);
    __syncthreads();
  }

  if (MODE == 0 || n0 < 1280) {
    if (MODE == 1) {
      const float* stab = (n0 < 1024) ? qs : ks;
      float sc0 = stab[fr], sc1 = stab[16 + fr], sc2 = stab[32 + fr], sc3 = stab[48 + fr];
#pragma unroll
      for (int m = 0; m < 4; ++m)
#pragma unroll
        for (int r = 0; r < 4; ++r) {
          const int row = m0 + wr * 64 + m * 16 + fq * 4 + r;
          const int t = row & (T_SEQ - 1);
          float ss = acc[m][0][r] * acc[m][0][r] + acc[m][1][r] * acc[m][1][r]
                   + acc[m][2][r] * acc[m][2][r] + acc[m][3][r] * acc[m][3][r];
          ss += __shfl_xor(ss, 1);
          ss += __shfl_xor(ss, 2);
          ss += __shfl_xor(ss, 4);
          ss += __shfl_xor(ss, 8);
          const float nrm = rsqrtf(ss * (1.f / 64.f) + 1e-6f);
          const float v0 = acc[m][0][r] * nrm * sc0;
          const float v1 = acc[m][1][r] * nrm * sc1;
          const float v2 = acc[m][2][r] * nrm * sc2;
          const float v3 = acc[m][3][r] * nrm * sc3;
          const float c = cosb[t * 16 + fr];
          const float s = sinb[t * 16 + fr];
          const float r0 = v0 * c - v1 * s;
          const float r1 = v0 * s + v1 * c;
          bf16_t* p = (bf16_t*)C + (size_t)row * ldC + n0 + wc * 64 + fr;
          p[0]  = __float2bfloat16(r0);
          p[16] = __float2bfloat16(r1);
          p[32] = __float2bfloat16(v2);
          p[48] = __float2bfloat16(v3);
        }
    } else {
#pragma unroll
      for (int m = 0; m < 4; ++m)
#pragma unroll
        for (int n = 0; n < 4; ++n)
#pragma unroll
          for (int r = 0; r < 4; ++r) {
            const int row = wr * 64 + m * 16 + fq * 4 + r;
            const int col = wc * 64 + n * 16 + fr;
            storeC(&C[(size_t)(m0 + row) * ldC + n0 + col], acc[m][n][r]);
          }
    }
  } else {
#pragma unroll
    for (int m = 0; m < 4; ++m) {
      const int row0 = m0 + wr * 64 + m * 16 + fq * 4;
      const int b = row0 >> 11, t0 = row0 & (T_SEQ - 1);
#pragma unroll
      for (int n = 0; n < 4; ++n) {
        const int vcol = n0 - 1280 + wc * 64 + n * 16 + fr;
        const int g = b * 4 + (vcol >> 6);
        const int d = vcol & 63;
        uint2 pk2;
        pk2.x = cvtpk(acc[m][n][0], acc[m][n][1]);
        pk2.y = cvtpk(acc[m][n][2], acc[m][n][3]);
        *(uint2*)(v_t + ((size_t)g * HD + d) * T_SEQ + t0) = pk2;
      }
    }
  }
}

// ---------------------------------------------------------------------------
// Causal GQA flash attention v13 — split-k by tile parity inside the round.
// Block = 8 waves = 4 strip-pairs; wave pair (2j,2j+1) shares strip
// sA=4p+j (pass 0) / 63-sA (pass 1); wave h=w&1 consumes subtile parity h
// of each KVBLK=64 round. Same rounds, same staging, 2x resident waves
// (grid 512 x 8 waves = 16 waves/CU). Online-softmax partials merged per
// pass via LDS (stride-padded), h=0 stores. Per-tile math identical to v12.
// ---------------------------------------------------------------------------
__global__ __launch_bounds__(512) void attn(
    const bf16_t* __restrict__ qkv, const bf16_t* __restrict__ v_t,
    bf16_t* __restrict__ y)
{
  __shared__ int4 lds[2048];      // 32 KB: dbuf x (K 8KB + V 8KB)
  const int tid  = threadIdx.x;   // 0..511
  const int lane = tid & 63;
  const int w    = tid >> 6;      // 0..7
  const int spair= w >> 1;        // 0..3: strip within block
  const int h    = w & 1;         // split-k parity
  const int ql   = lane & 31;
  const int hi   = lane >> 5;
  const int id   = (int)blockIdx.x;          // 0..511
  const int low3 = id & 7;
  const int rest = id >> 3;                  // 0..63
  const int gsel = rest & 1;
  const int hh   = (rest >> 1) & 3;
  const int p    = rest >> 3;                // 0..7
  const int g16  = low3 + 8 * gsel;          // b*4+kvh (same-XCD clustering)
  const int b    = g16 >> 2, kvh = g16 & 3;
  const int hd   = kvh * 4 + hh;
  const int sA   = 4 * p + spair;            // pass-0 strip; pass-1 = 63-sA
  const float SCALE_LOG2 = 0.125f * 1.44269504089f;

  // staging: 512 threads cover both subtiles (u = tid>>8) of K and V
  const int sid = tid & 255;
  const int u   = tid >> 8;
  const int kr = sid >> 3, kslot = sid & 7;
  const int vd = sid >> 2, vslot = sid & 3;
  const bf16_t* gK = qkv + (size_t)(b * T_SEQ + kr + u * 32) * LDQKV + 1024 + kvh * HD + kslot * 8;
  const bf16_t* gV = v_t + (size_t)((b * N_KV + kvh) * HD + vd) * T_SEQ + vslot * 8 + u * 32;
  const int wKidx = u * 256 + kr * 8 + (kslot ^ (kr & 7));
  const int wVidx = 512 + u * 256 + vd * 4 + (vslot ^ ((vd >> 1) & 3));

  // fragment read indices (subtile-relative; + h*256 + buf*1024)
  int kridx[4];
#pragma unroll
  for (int c = 0; c < 4; ++c)
    kridx[c] = ql * 8 + ((2 * c + hi) ^ (ql & 7));
  const int vsw = (ql >> 1) & 3;
  const int v0idx = 512 + ql * 4 + (hi ^ vsw);
  const int v1idx = 512 + ql * 4 + ((2 + hi) ^ vsw);
  const int v2idx = 512 + (ql + 32) * 4 + (hi ^ vsw);
  const int v3idx = 512 + (ql + 32) * 4 + ((2 + hi) ^ vsw);

  union ob { unsigned uu[4]; bf16x8 v; } onesf;
#pragma unroll
  for (int i = 0; i < 4; ++i) onesf.uu[i] = 0x3F803F80u;

  f32x16 zro;
#pragma unroll
  for (int i = 0; i < 16; ++i) zro[i] = 0.f;

  float* lf = (float*)lds;
  int buf = 0;
#pragma unroll
  for (int pi = 0; pi < 2; ++pi) {
    const int s = pi ? (63 - sA) : sA;
    const int q_glob = s * 32 + ql;
    const int nt = s + 1;                              // strip's 32-k tiles
    const int nR = pi ? (32 - 2 * p) : (2 * p + 2);    // block-uniform rounds

    // Q fragments, pre-scaled into log2 domain (same for both pair waves)
    const bf16_t* Qrow = qkv + (size_t)(b * T_SEQ + q_glob) * LDQKV + hd * HD + hi * 8;
    bf16x8 qfrag[4];
#pragma unroll
    for (int c = 0; c < 4; ++c) {
      bf16x8 raw = *(const bf16x8*)(Qrow + c * 16);
      bf16x8 sc;
#pragma unroll
      for (int j = 0; j < 8; ++j)
        sc[j] = (__bf16)((float)raw[j] * SCALE_LOG2);
      qfrag[c] = sc;
    }

    f32x16 acc0, acc1, accL;
#pragma unroll
    for (int i = 0; i < 16; ++i) { acc0[i] = 0.f; acc1[i] = 0.f; accL[i] = 0.f; }
    float m_run = -1e30f;

    // prologue: stage round-0 pair into current buf
    {
      int4 kA = *(const int4*)gK;
      int4 vA = *(const int4*)gV;
      const int nb = buf * 1024;
      lds[nb + wKidx] = kA;
      lds[nb + wVidx] = vA;
    }
    __syncthreads();

    for (int r = 0; r < nR; ++r) {
      int4 kA, vA;
      const bool more = (r + 1 < nR);
      if (more) {
        kA = *(const int4*)(gK + (size_t)(r + 1) * 64 * LDQKV);
        vA = *(const int4*)(gV + (r + 1) * 64);
      }

      const int t = 2 * r + h;     // this wave's tile (parity split)
      if (t < nt) {
        const int k0 = t << 5;
        const bool masked = (t == nt - 1);
        const int base = buf * 1024 + h * 256;

        bf16x8 kf0 = *(const bf16x8*)&lds[base + kridx[0]];
        bf16x8 kf1 = *(const bf16x8*)&lds[base + kridx[1]];
        bf16x8 kf2 = *(const bf16x8*)&lds[base + kridx[2]];
        bf16x8 kf3 = *(const bf16x8*)&lds[base + kridx[3]];

        __builtin_amdgcn_s_setprio(1);
        f32x16 st = __builtin_amdgcn_mfma_f32_32x32x16_bf16(kf0, qfrag[0], zro, 0, 0, 0);
        st = __builtin_amdgcn_mfma_f32_32x32x16_bf16(kf1, qfrag[1], st, 0, 0, 0);
        st = __builtin_amdgcn_mfma_f32_32x32x16_bf16(kf2, qfrag[2], st, 0, 0, 0);
        st = __builtin_amdgcn_mfma_f32_32x32x16_bf16(kf3, qfrag[3], st, 0, 0, 0);
        __builtin_amdgcn_s_setprio(0);

        if (masked) {
#pragma unroll
          for (int rr = 0; rr < 16; ++rr) {
            const int kg = k0 + (rr & 3) + 8 * (rr >> 2) + 4 * hi;
            if (kg > q_glob) st[rr] = -1e30f;
          }
        }
        float m01 = fmaxf(fmaxf(st[0], st[1]), st[2]);
        float m02 = fmaxf(fmaxf(st[3], st[4]), st[5]);
        float m03 = fmaxf(fmaxf(st[6], st[7]), st[8]);
        float m04 = fmaxf(fmaxf(st[9], st[10]), st[11]);
        float m05 = fmaxf(fmaxf(st[12], st[13]), st[14]);
        float m06 = fmaxf(fmaxf(m01, m02), m03);
        float m07 = fmaxf(fmaxf(m04, m05), st[15]);
        const float bmax = fmaxf(m06, m07);
        if (__any(bmax > m_run + 8.f)) {        // T13 defer-max
          const float rmax = fmaxf(bmax, __shfl_xor(bmax, 32));
          const float mnew = fmaxf(m_run, rmax);
          const float corr = fexp2(m_run - mnew);
#pragma unroll
          for (int i = 0; i < 16; ++i) { acc0[i] *= corr; acc1[i] *= corr; }
          accL[0] *= corr;
          m_run = mnew;
        }
        float pp[16];
#pragma unroll
        for (int rr = 0; rr < 16; ++rr) pp[rr] = fexp2(st[rr] - m_run);

        unsigned wp[8];
#pragma unroll
        for (int i = 0; i < 8; ++i) wp[i] = cvtpk(pp[2 * i], pp[2 * i + 1]);
        plswap(wp[0], wp[2]); plswap(wp[1], wp[3]);
        plswap(wp[4], wp[6]); plswap(wp[5], wp[7]);
        union fu { unsigned uu[4]; bf16x8 v; };
        fu f1, f2;
        f1.uu[0] = wp[0]; f1.uu[1] = wp[1]; f1.uu[2] = wp[2]; f1.uu[3] = wp[3];
        f2.uu[0] = wp[4]; f2.uu[1] = wp[5]; f2.uu[2] = wp[6]; f2.uu[3] = wp[7];

        bf16x8 vf0 = *(const bf16x8*)&lds[base + v0idx];
        bf16x8 vf1 = *(const bf16x8*)&lds[base + v1idx];
        bf16x8 vf2 = *(const bf16x8*)&lds[base + v2idx];
        bf16x8 vf3 = *(const bf16x8*)&lds[base + v3idx];

        __builtin_amdgcn_s_setprio(1);
        acc0 = __builtin_amdgcn_mfma_f32_32x32x16_bf16(vf0, f1.v, acc0, 0, 0, 0);
        acc0 = __builtin_amdgcn_mfma_f32_32x32x16_bf16(vf1, f2.v, acc0, 0, 0, 0);
        acc1 = __builtin_amdgcn_mfma_f32_32x32x16_bf16(vf2, f1.v, acc1, 0, 0, 0);
        acc1 = __builtin_amdgcn_mfma_f32_32x32x16_bf16(vf3, f2.v, acc1, 0, 0, 0);
        accL = __builtin_amdgcn_mfma_f32_32x32x16_bf16(onesf.v, f1.v, accL, 0, 0, 0);
        accL = __builtin_amdgcn_mfma_f32_32x32x16_bf16(onesf.v, f2.v, accL, 0, 0, 0);
        __builtin_amdgcn_s_setprio(0);
      }

      if (more) {
        const int nb = (buf ^ 1) * 1024;
        lds[nb + wKidx] = kA;
        lds[nb + wVidx] = vA;
      }
      __syncthreads();
      buf ^= 1;
    }

    // ---- split-k merge: h=1 publishes partials, h=0 merges & stores ----
    float cA = 1.f, cB = 0.f, l_mrg = 0.f;
    if (h == 1) {
      const int fb = spair * 1216 + lane * 19;
#pragma unroll
      for (int i = 0; i < 16; ++i) lf[fb + i] = acc0[i];
      lf[fb + 16] = m_run;
      lf[fb + 17] = accL[0];
    }
    __syncthreads();
    if (h == 0) {
      const int fb = spair * 1216 + lane * 19;
      const float mB = lf[fb + 16], lB = lf[fb + 17];
      const float mM = fmaxf(m_run, mB);
      cA = fexp2(m_run - mM);
      cB = fexp2(mB - mM);
      l_mrg = accL[0] * cA + lB * cB;
#pragma unroll
      for (int i = 0; i < 16; ++i) acc0[i] = acc0[i] * cA + lf[fb + i] * cB;
    }
    __syncthreads();
    if (h == 1) {
      const int fb2 = spair * 1088 + lane * 17;
#pragma unroll
      for (int i = 0; i < 16; ++i) lf[fb2 + i] = acc1[i];
    }
    __syncthreads();
    if (h == 0) {
      const int fb2 = spair * 1088 + lane * 17;
#pragma unroll
      for (int i = 0; i < 16; ++i) acc1[i] = acc1[i] * cA + lf[fb2 + i] * cB;
      const float inv = 1.f / l_mrg;
      bf16_t* yrow = y + (size_t)(b * T_SEQ + q_glob) * D_MODEL + hd * HD;
#pragma unroll
      for (int gg = 0; gg < 4; ++gg) {
        uint2 o0, o1;
        o0.x = cvtpk(acc0[4 * gg + 0] * inv, acc0[4 * gg + 1] * inv);
        o0.y = cvtpk(acc0[4 * gg + 2] * inv, acc0[4 * gg + 3] * inv);
        o1.x = cvtpk(acc1[4 * gg + 0] * inv, acc1[4 * gg + 1] * inv);
        o1.y = cvtpk(acc1[4 * gg + 2] * inv, acc1[4 * gg + 3] * inv);
        *(uint2*)(yrow + 8 * gg + 4 * hi)      = o0;
        *(uint2*)(yrow + 32 + 8 * gg + 4 * hi) = o1;
      }
    }
    __syncthreads();   // fence LDS reads before next pass's prologue writes
  }
}

// ---------------------------------------------------------------------------
extern "C" void kernel_launch(void* const* d_in, const int* in_sizes, int n_in,
                              void* d_out, int out_size, void* d_ws,
                              size_t ws_size, hipStream_t stream) {
  const float* x    = (const float*)d_in[0];
  const float* cosb = (const float*)d_in[1];
  const float* sinb = (const float*)d_in[2];
  const float* Wq   = (const float*)d_in[3];
  const float* Wk   = (const float*)d_in[4];
  const float* Wv   = (const float*)d_in[5];
  const float* Wo   = (const float*)d_in[6];
  const float* qs   = (const float*)d_in[7];
  const float* ks   = (const float*)d_in[8];
  float* out = (float*)d_out;   // reference output dtype is float32

  char* ws = (char*)d_ws;
  bf16_t* qkv   = (bf16_t*)ws;                       // 25165824 B
  bf16_t* v_t   = (bf16_t*)(ws + 25165824);          // 4194304 B
  bf16_t* y     = (bf16_t*)(ws + 29360128);          // 16777216 B (= xb alias)
  bf16_t* xb    = y;                                 // xb dead before attn writes y
  bf16_t* wqkvb = (bf16_t*)(ws + 46137344);          // 3145728 B
  bf16_t* wob   = (bf16_t*)(ws + 49283072);          // 2097152 B

  // 0. fp32 -> bf16 converts (one launch: x + all weights)
  all_cvt<<<dim3(2688), 256, 0, stream>>>(x, Wq, Wk, Wv, Wo, xb, wqkvb, wob);

  // 1. fused QKV projection + RMSNorm + RoPE + V-transpose
  gemm_bb<1, bf16_t><<<dim3(12, 64), 256, 0, stream>>>(
      xb, wqkvb, qkv, LDQKV, cosb, sinb, qs, ks, v_t);
  // 2. causal GQA flash attention -> y (8-wave split-k blocks)
  attn<<<dim3(512), 512, 0, stream>>>(qkv, v_t, y);
  // 3. output projection
  gemm_bb<0, float><<<dim3(8, 64), 256, 0, stream>>>(
      y, wob, out, D_MODEL, nullptr, nullptr, nullptr, nullptr, nullptr);
}

// Round 18
// 158.783 us; speedup vs baseline: 1.5125x; 1.0094x over previous
//
#include <hip/hip_runtime.h>
#include <hip/hip_bf16.h>
#include <stdint.h>

typedef __attribute__((ext_vector_type(8)))  __bf16 bf16x8;
typedef __attribute__((ext_vector_type(4)))  float  f32x4;
typedef __attribute__((ext_vector_type(16))) float  f32x16;
typedef __hip_bfloat16 bf16_t;

#define T_SEQ 2048
#define D_MODEL 1024
#define N_HEADS 16
#define N_KV 4
#define HD 64
#define LDQKV 1536
#define KDIM 1024

// Convert 16 consecutive fp32 (4x float4) -> 16 bf16 (2x int4)
__device__ inline void cvt16(const float4* __restrict__ g, int4* __restrict__ s) {
  float4 v0 = g[0], v1 = g[1], v2 = g[2], v3 = g[3];
  union { int4 i[2]; __hip_bfloat162 h[8]; } u;
  u.h[0] = __float22bfloat162_rn(make_float2(v0.x, v0.y));
  u.h[1] = __float22bfloat162_rn(make_float2(v0.z, v0.w));
  u.h[2] = __float22bfloat162_rn(make_float2(v1.x, v1.y));
  u.h[3] = __float22bfloat162_rn(make_float2(v1.z, v1.w));
  u.h[4] = __float22bfloat162_rn(make_float2(v2.x, v2.y));
  u.h[5] = __float22bfloat162_rn(make_float2(v2.z, v2.w));
  u.h[6] = __float22bfloat162_rn(make_float2(v3.x, v3.y));
  u.h[7] = __float22bfloat162_rn(make_float2(v3.z, v3.w));
  s[0] = u.i[0]; s[1] = u.i[1];
}

__device__ inline void storeC(bf16_t* p, float v) { *p = __float2bfloat16(v); }
__device__ inline void storeC(float* p, float v) { *p = v; }

// v_permlane32_swap_b32 vdst, vsrc: after plswap(a,b): a={a_L,b_L}, b={a_U,b_U}
__device__ inline void plswap(unsigned& a, unsigned& b) {
  asm volatile("v_permlane32_swap_b32 %0, %1" : "+v"(a), "+v"(b));
}

// HW transcendental exp2 (input already in log2 domain)
__device__ inline float fexp2(float x) {
  float r; asm("v_exp_f32 %0, %1" : "=v"(r) : "v"(x)); return r;
}
// HW packed fp32->bf16 (T12 recipe; no builtin on gfx950)
__device__ inline unsigned cvtpk(float lo, float hi) {
  unsigned r; asm("v_cvt_pk_bf16_f32 %0, %1, %2" : "=v"(r) : "v"(lo), "v"(hi));
  return r;
}

// async global->LDS, 16B per lane; lds dest must be wave-uniform base.
__device__ inline void gll16(const bf16_t* g, bf16_t* l) {
  __builtin_amdgcn_global_load_lds(
      (const __attribute__((address_space(1))) void*)g,
      (__attribute__((address_space(3))) void*)l, 16, 0, 0);
}

// ---------------------------------------------------------------------------
// fp32 -> bf16 bulk convert, x + all weights in ONE launch (units of 16 elem)
// ---------------------------------------------------------------------------
__global__ __launch_bounds__(256) void all_cvt(
    const float* __restrict__ x,
    const float* __restrict__ Wq, const float* __restrict__ Wk,
    const float* __restrict__ Wv, const float* __restrict__ Wo,
    bf16_t* __restrict__ xb, bf16_t* __restrict__ wqkvb,
    bf16_t* __restrict__ wob) {
  const int i = blockIdx.x * 256 + threadIdx.x;
  const float* s; bf16_t* d; int off;
  if (i < 524288)      { s = x;  d = xb;                   off = i; }
  else if (i < 589824) { s = Wq; d = wqkvb;                off = i - 524288; }
  else if (i < 606208) { s = Wk; d = wqkvb + 1024 * 1024;  off = i - 589824; }
  else if (i < 622592) { s = Wv; d = wqkvb + 1280 * 1024;  off = i - 606208; }
  else                 { s = Wo; d = wob;                  off = i - 622592; }
  cvt16((const float4*)s + off * 4, (int4*)d + off * 2);
}

// ---------------------------------------------------------------------------
// GEMM bf16 x bf16 (unchanged — passing, fused QKV epilogue)
// ---------------------------------------------------------------------------
template <int MODE, typename CT>
__global__ __launch_bounds__(256) void gemm_bb(
    const bf16_t* __restrict__ A, const bf16_t* __restrict__ W,
    CT* __restrict__ C, const int ldC,
    const float* __restrict__ cosb, const float* __restrict__ sinb,
    const float* __restrict__ qs, const float* __restrict__ ks,
    bf16_t* __restrict__ v_t)
{
  __shared__ bf16_t As[128 * 32];
  __shared__ bf16_t Bs[128 * 32];
  const int tid = threadIdx.x;
  const int lane = tid & 63;
  const int wv = tid >> 6;
  const int wr = wv >> 1, wc = wv & 1;
  const int m0 = blockIdx.y * 128;
  const int n0 = blockIdx.x * 128;

  const int srow = lane >> 2;
  const int scol = (lane & 3) * 8;
  const bf16_t* gA = A + (size_t)(m0 + 32 * wv + srow) * KDIM + scol;
  const bf16_t* gB = W + (size_t)(n0 + 32 * wv + srow) * KDIM + scol;
  bf16_t* lA = As + wv * 1024;
  bf16_t* lB = Bs + wv * 1024;

  f32x4 acc[4][4];
#pragma unroll
  for (int m = 0; m < 4; ++m)
#pragma unroll
    for (int n = 0; n < 4; ++n)
      acc[m][n] = {0.f, 0.f, 0.f, 0.f};

  const int fr = lane & 15;
  const int fq = lane >> 4;

  for (int k0 = 0; k0 < KDIM; k0 += 32) {
    gll16(gA + k0, lA);
    gll16(gA + 16 * KDIM + k0, lA + 512);
    gll16(gB + k0, lB);
    gll16(gB + 16 * KDIM + k0, lB + 512);
    __syncthreads();
    bf16x8 af[4], bfv[4];
#pragma unroll
    for (int m = 0; m < 4; ++m)
      af[m] = *(const bf16x8*)(&As[(wr * 64 + m * 16 + fr) * 32 + fq * 8]);
#pragma unroll
    for (int n = 0; n < 4; ++n)
      bfv[n] = *(const bf16x8*)(&Bs[(wc * 64 + n * 16 + fr) * 32 + fq * 8]);
#pragma unroll
    for (int m = 0; m < 4; ++m)
#pragma unroll
      for (int n = 0; n < 4; ++n)
        acc[m][n] = __builtin_amdgcn_mfma_f32_16x16x32_bf16(af[m], bfv[n],
                                                            acc[m][n], 0, 0, 0);
    __syncthreads();
  }

  if (MODE == 0 || n0 < 1280) {
    if (MODE == 1) {
      const float* stab = (n0 < 1024) ? qs : ks;
      float sc0 = stab[fr], sc1 = stab[16 + fr], sc2 = stab[32 + fr], sc3 = stab[48 + fr];
#pragma unroll
      for (int m = 0; m < 4; ++m)
#pragma unroll
        for (int r = 0; r < 4; ++r) {
          const int row = m0 + wr * 64 + m * 16 + fq * 4 + r;
          const int t = row & (T_SEQ - 1);
          float ss = acc[m][0][r] * acc[m][0][r] + acc[m][1][r] * acc[m][1][r]
                   + acc[m][2][r] * acc[m][2][r] + acc[m][3][r] * acc[m][3][r];
          ss += __shfl_xor(ss, 1);
          ss += __shfl_xor(ss, 2);
          ss += __shfl_xor(ss, 4);
          ss += __shfl_xor(ss, 8);
          const float nrm = rsqrtf(ss * (1.f / 64.f) + 1e-6f);
          const float v0 = acc[m][0][r] * nrm * sc0;
          const float v1 = acc[m][1][r] * nrm * sc1;
          const float v2 = acc[m][2][r] * nrm * sc2;
          const float v3 = acc[m][3][r] * nrm * sc3;
          const float c = cosb[t * 16 + fr];
          const float s = sinb[t * 16 + fr];
          const float r0 = v0 * c - v1 * s;
          const float r1 = v0 * s + v1 * c;
          bf16_t* p = (bf16_t*)C + (size_t)row * ldC + n0 + wc * 64 + fr;
          p[0]  = __float2bfloat16(r0);
          p[16] = __float2bfloat16(r1);
          p[32] = __float2bfloat16(v2);
          p[48] = __float2bfloat16(v3);
        }
    } else {
#pragma unroll
      for (int m = 0; m < 4; ++m)
#pragma unroll
        for (int n = 0; n < 4; ++n)
#pragma unroll
          for (int r = 0; r < 4; ++r) {
            const int row = wr * 64 + m * 16 + fq * 4 + r;
            const int col = wc * 64 + n * 16 + fr;
            storeC(&C[(size_t)(m0 + row) * ldC + n0 + col], acc[m][n][r]);
          }
    }
  } else {
#pragma unroll
    for (int m = 0; m < 4; ++m) {
      const int row0 = m0 + wr * 64 + m * 16 + fq * 4;
      const int b = row0 >> 11, t0 = row0 & (T_SEQ - 1);
#pragma unroll
      for (int n = 0; n < 4; ++n) {
        const int vcol = n0 - 1280 + wc * 64 + n * 16 + fr;
        const int g = b * 4 + (vcol >> 6);
        const int d = vcol & 63;
        uint2 pk2;
        pk2.x = cvtpk(acc[m][n][0], acc[m][n][1]);
        pk2.y = cvtpk(acc[m][n][2], acc[m][n][3]);
        *(uint2*)(v_t + ((size_t)g * HD + d) * T_SEQ + t0) = pk2;
      }
    }
  }
}

// ---------------------------------------------------------------------------
// Causal GQA flash attention v14 — v13 (8-wave split-k paired) with
// KVBLK=128: each barrier round stages FOUR 32-k subtiles (K 16KB + V 16KB,
// dbuf = 64KB LDS, 2 blocks/CU). Wave parity h consumes subtiles {2h,2h+1}.
// Rounds/block: 34 -> 17 (pass0 p+1, pass1 16-p; block-uniform). Per-tile
// math, swizzles, and split-k merge identical to v13 (passing).
// ---------------------------------------------------------------------------
__global__ __launch_bounds__(512) void attn(
    const bf16_t* __restrict__ qkv, const bf16_t* __restrict__ v_t,
    bf16_t* __restrict__ y)
{
  __shared__ int4 lds[4096];      // 64 KB: dbuf x (K 16KB + V 16KB)
  const int tid  = threadIdx.x;   // 0..511
  const int lane = tid & 63;
  const int w    = tid >> 6;      // 0..7
  const int spair= w >> 1;        // 0..3: strip within block
  const int h    = w & 1;         // split-k parity (subtile pair {2h,2h+1})
  const int ql   = lane & 31;
  const int hi   = lane >> 5;
  const int id   = (int)blockIdx.x;          // 0..511
  const int low3 = id & 7;
  const int rest = id >> 3;                  // 0..63
  const int gsel = rest & 1;
  const int hh   = (rest >> 1) & 3;
  const int p    = rest >> 3;                // 0..7
  const int g16  = low3 + 8 * gsel;          // b*4+kvh (same-XCD clustering)
  const int b    = g16 >> 2, kvh = g16 & 3;
  const int hd   = kvh * 4 + hh;
  const int sA   = 4 * p + spair;            // pass-0 strip; pass-1 = 63-sA
  const float SCALE_LOG2 = 0.125f * 1.44269504089f;

  // staging: 512 threads; thread covers subtiles u2 and u2+2 (u2 = tid>>8)
  const int sid = tid & 255;
  const int u2  = tid >> 8;
  const int kr = sid >> 3, kslot = sid & 7;
  const int vd = sid >> 2, vslot = sid & 3;
  const bf16_t* gK = qkv + (size_t)(b * T_SEQ + kr + u2 * 32) * LDQKV + 1024 + kvh * HD + kslot * 8;
  const bf16_t* gV = v_t + (size_t)((b * N_KV + kvh) * HD + vd) * T_SEQ + vslot * 8 + u2 * 32;
  const int wK0 = u2 * 256 + kr * 8 + (kslot ^ (kr & 7));          // +buf*2048; 2nd subtile +512
  const int wV0 = 1024 + u2 * 256 + vd * 4 + (vslot ^ ((vd >> 1) & 3));

  // fragment read indices (subtile-relative)
  int kridx[4];
#pragma unroll
  for (int c = 0; c < 4; ++c)
    kridx[c] = ql * 8 + ((2 * c + hi) ^ (ql & 7));
  const int vsw = (ql >> 1) & 3;
  const int v0r = ql * 4 + (hi ^ vsw);
  const int v1r = ql * 4 + ((2 + hi) ^ vsw);
  const int v2r = (ql + 32) * 4 + (hi ^ vsw);
  const int v3r = (ql + 32) * 4 + ((2 + hi) ^ vsw);

  union ob { unsigned uu[4]; bf16x8 v; } onesf;
#pragma unroll
  for (int i = 0; i < 4; ++i) onesf.uu[i] = 0x3F803F80u;

  f32x16 zro;
#pragma unroll
  for (int i = 0; i < 16; ++i) zro[i] = 0.f;

  float* lf = (float*)lds;
  int buf = 0;
#pragma unroll
  for (int pi = 0; pi < 2; ++pi) {
    const int s = pi ? (63 - sA) : sA;
    const int q_glob = s * 32 + ql;
    const int nt = s + 1;                       // strip's 32-k tiles
    const int nR = pi ? (16 - p) : (p + 1);     // block-uniform 128-k rounds

    // Q fragments, pre-scaled into log2 domain
    const bf16_t* Qrow = qkv + (size_t)(b * T_SEQ + q_glob) * LDQKV + hd * HD + hi * 8;
    bf16x8 qfrag[4];
#pragma unroll
    for (int c = 0; c < 4; ++c) {
      bf16x8 raw = *(const bf16x8*)(Qrow + c * 16);
      bf16x8 sc;
#pragma unroll
      for (int j = 0; j < 8; ++j)
        sc[j] = (__bf16)((float)raw[j] * SCALE_LOG2);
      qfrag[c] = sc;
    }

    f32x16 acc0, acc1, accL;
#pragma unroll
    for (int i = 0; i < 16; ++i) { acc0[i] = 0.f; acc1[i] = 0.f; accL[i] = 0.f; }
    float m_run = -1e30f;

    // prologue: stage round-0 (4 subtiles) into current buf
    {
      int4 a0 = *(const int4*)gK;
      int4 a1 = *(const int4*)(gK + (size_t)64 * LDQKV);
      int4 a2 = *(const int4*)gV;
      int4 a3 = *(const int4*)(gV + 64);
      const int nb = buf * 2048;
      lds[nb + wK0] = a0; lds[nb + wK0 + 512] = a1;
      lds[nb + wV0] = a2; lds[nb + wV0 + 512] = a3;
    }
    __syncthreads();

    for (int r = 0; r < nR; ++r) {
      int4 kA0, kA1, vA0, vA1;
      const bool more = (r + 1 < nR);
      if (more) {
        const bf16_t* k1 = gK + (size_t)(r + 1) * 128 * LDQKV;
        const bf16_t* v1 = gV + (r + 1) * 128;
        kA0 = *(const int4*)k1;
        kA1 = *(const int4*)(k1 + (size_t)64 * LDQKV);
        vA0 = *(const int4*)v1;
        vA1 = *(const int4*)(v1 + 64);
      }

#pragma unroll
      for (int uu = 0; uu < 2; ++uu) {
        const int t = 4 * r + 2 * h + uu;
        if (t < nt) {
          const int k0 = t << 5;
          const bool masked = (t == nt - 1);
          const int su = 2 * h + uu;              // == t & 3
          const int kbase = buf * 2048 + su * 256;
          const int vbase = buf * 2048 + 1024 + su * 256;

          bf16x8 kf0 = *(const bf16x8*)&lds[kbase + kridx[0]];
          bf16x8 kf1 = *(const bf16x8*)&lds[kbase + kridx[1]];
          bf16x8 kf2 = *(const bf16x8*)&lds[kbase + kridx[2]];
          bf16x8 kf3 = *(const bf16x8*)&lds[kbase + kridx[3]];

          __builtin_amdgcn_s_setprio(1);
          f32x16 st = __builtin_amdgcn_mfma_f32_32x32x16_bf16(kf0, qfrag[0], zro, 0, 0, 0);
          st = __builtin_amdgcn_mfma_f32_32x32x16_bf16(kf1, qfrag[1], st, 0, 0, 0);
          st = __builtin_amdgcn_mfma_f32_32x32x16_bf16(kf2, qfrag[2], st, 0, 0, 0);
          st = __builtin_amdgcn_mfma_f32_32x32x16_bf16(kf3, qfrag[3], st, 0, 0, 0);
          __builtin_amdgcn_s_setprio(0);

          if (masked) {
#pragma unroll
            for (int rr = 0; rr < 16; ++rr) {
              const int kg = k0 + (rr & 3) + 8 * (rr >> 2) + 4 * hi;
              if (kg > q_glob) st[rr] = -1e30f;
            }
          }
          float m01 = fmaxf(fmaxf(st[0], st[1]), st[2]);
          float m02 = fmaxf(fmaxf(st[3], st[4]), st[5]);
          float m03 = fmaxf(fmaxf(st[6], st[7]), st[8]);
          float m04 = fmaxf(fmaxf(st[9], st[10]), st[11]);
          float m05 = fmaxf(fmaxf(st[12], st[13]), st[14]);
          float m06 = fmaxf(fmaxf(m01, m02), m03);
          float m07 = fmaxf(fmaxf(m04, m05), st[15]);
          const float bmax = fmaxf(m06, m07);
          if (__any(bmax > m_run + 8.f)) {        // T13 defer-max
            const float rmax = fmaxf(bmax, __shfl_xor(bmax, 32));
            const float mnew = fmaxf(m_run, rmax);
            const float corr = fexp2(m_run - mnew);
#pragma unroll
            for (int i = 0; i < 16; ++i) { acc0[i] *= corr; acc1[i] *= corr; }
            accL[0] *= corr;
            m_run = mnew;
          }
          float pp[16];
#pragma unroll
          for (int rr = 0; rr < 16; ++rr) pp[rr] = fexp2(st[rr] - m_run);

          unsigned wp[8];
#pragma unroll
          for (int i = 0; i < 8; ++i) wp[i] = cvtpk(pp[2 * i], pp[2 * i + 1]);
          plswap(wp[0], wp[2]); plswap(wp[1], wp[3]);
          plswap(wp[4], wp[6]); plswap(wp[5], wp[7]);
          union fu { unsigned uu2[4]; bf16x8 v; };
          fu f1, f2;
          f1.uu2[0] = wp[0]; f1.uu2[1] = wp[1]; f1.uu2[2] = wp[2]; f1.uu2[3] = wp[3];
          f2.uu2[0] = wp[4]; f2.uu2[1] = wp[5]; f2.uu2[2] = wp[6]; f2.uu2[3] = wp[7];

          bf16x8 vf0 = *(const bf16x8*)&lds[vbase + v0r];
          bf16x8 vf1 = *(const bf16x8*)&lds[vbase + v1r];
          bf16x8 vf2 = *(const bf16x8*)&lds[vbase + v2r];
          bf16x8 vf3 = *(const bf16x8*)&lds[vbase + v3r];

          __builtin_amdgcn_s_setprio(1);
          acc0 = __builtin_amdgcn_mfma_f32_32x32x16_bf16(vf0, f1.v, acc0, 0, 0, 0);
          acc0 = __builtin_amdgcn_mfma_f32_32x32x16_bf16(vf1, f2.v, acc0, 0, 0, 0);
          acc1 = __builtin_amdgcn_mfma_f32_32x32x16_bf16(vf2, f1.v, acc1, 0, 0, 0);
          acc1 = __builtin_amdgcn_mfma_f32_32x32x16_bf16(vf3, f2.v, acc1, 0, 0, 0);
          accL = __builtin_amdgcn_mfma_f32_32x32x16_bf16(onesf.v, f1.v, accL, 0, 0, 0);
          accL = __builtin_amdgcn_mfma_f32_32x32x16_bf16(onesf.v, f2.v, accL, 0, 0, 0);
          __builtin_amdgcn_s_setprio(0);
        }
      }

      if (more) {
        const int nb = (buf ^ 1) * 2048;
        lds[nb + wK0] = kA0; lds[nb + wK0 + 512] = kA1;
        lds[nb + wV0] = vA0; lds[nb + wV0 + 512] = vA1;
      }
      __syncthreads();
      buf ^= 1;
    }

    // ---- split-k merge: h=1 publishes partials, h=0 merges & stores ----
    float cA = 1.f, cB = 0.f, l_mrg = 0.f;
    if (h == 1) {
      const int fb = spair * 1216 + lane * 19;
#pragma unroll
      for (int i = 0; i < 16; ++i) lf[fb + i] = acc0[i];
      lf[fb + 16] = m_run;
      lf[fb + 17] = accL[0];
    }
    __syncthreads();
    if (h == 0) {
      const int fb = spair * 1216 + lane * 19;
      const float mB = lf[fb + 16], lB = lf[fb + 17];
      const float mM = fmaxf(m_run, mB);
      cA = fexp2(m_run - mM);
      cB = fexp2(mB - mM);
      l_mrg = accL[0] * cA + lB * cB;
#pragma unroll
      for (int i = 0; i < 16; ++i) acc0[i] = acc0[i] * cA + lf[fb + i] * cB;
    }
    __syncthreads();
    if (h == 1) {
      const int fb2 = spair * 1088 + lane * 17;
#pragma unroll
      for (int i = 0; i < 16; ++i) lf[fb2 + i] = acc1[i];
    }
    __syncthreads();
    if (h == 0) {
      const int fb2 = spair * 1088 + lane * 17;
#pragma unroll
      for (int i = 0; i < 16; ++i) acc1[i] = acc1[i] * cA + lf[fb2 + i] * cB;
      const float inv = 1.f / l_mrg;
      bf16_t* yrow = y + (size_t)(b * T_SEQ + q_glob) * D_MODEL + hd * HD;
#pragma unroll
      for (int gg = 0; gg < 4; ++gg) {
        uint2 o0, o1;
        o0.x = cvtpk(acc0[4 * gg + 0] * inv, acc0[4 * gg + 1] * inv);
        o0.y = cvtpk(acc0[4 * gg + 2] * inv, acc0[4 * gg + 3] * inv);
        o1.x = cvtpk(acc1[4 * gg + 0] * inv, acc1[4 * gg + 1] * inv);
        o1.y = cvtpk(acc1[4 * gg + 2] * inv, acc1[4 * gg + 3] * inv);
        *(uint2*)(yrow + 8 * gg + 4 * hi)      = o0;
        *(uint2*)(yrow + 32 + 8 * gg + 4 * hi) = o1;
      }
    }
    __syncthreads();   // fence LDS reads before next pass's prologue writes
  }
}

// ---------------------------------------------------------------------------
extern "C" void kernel_launch(void* const* d_in, const int* in_sizes, int n_in,
                              void* d_out, int out_size, void* d_ws,
                              size_t ws_size, hipStream_t stream) {
  const float* x    = (const float*)d_in[0];
  const float* cosb = (const float*)d_in[1];
  const float* sinb = (const float*)d_in[2];
  const float* Wq   = (const float*)d_in[3];
  const float* Wk   = (const float*)d_in[4];
  const float* Wv   = (const float*)d_in[5];
  const float* Wo   = (const float*)d_in[6];
  const float* qs   = (const float*)d_in[7];
  const float* ks   = (const float*)d_in[8];
  float* out = (float*)d_out;   // reference output dtype is float32

  char* ws = (char*)d_ws;
  bf16_t* qkv   = (bf16_t*)ws;                       // 25165824 B
  bf16_t* v_t   = (bf16_t*)(ws + 25165824);          // 4194304 B
  bf16_t* y     = (bf16_t*)(ws + 29360128);          // 16777216 B (= xb alias)
  bf16_t* xb    = y;                                 // xb dead before attn writes y
  bf16_t* wqkvb = (bf16_t*)(ws + 46137344);          // 3145728 B
  bf16_t* wob   = (bf16_t*)(ws + 49283072);          // 2097152 B

  // 0. fp32 -> bf16 converts (one launch: x + all weights)
  all_cvt<<<dim3(2688), 256, 0, stream>>>(x, Wq, Wk, Wv, Wo, xb, wqkvb, wob);

  // 1. fused QKV projection + RMSNorm + RoPE + V-transpose
  gemm_bb<1, bf16_t><<<dim3(12, 64), 256, 0, stream>>>(
      xb, wqkvb, qkv, LDQKV, cosb, sinb, qs, ks, v_t);
  // 2. causal GQA flash attention -> y (8-wave split-k, KVBLK=128)
  attn<<<dim3(512), 512, 0, stream>>>(qkv, v_t, y);
  // 3. output projection
  gemm_bb<0, float><<<dim3(8, 64), 256, 0, stream>>>(
      y, wob, out, D_MODEL, nullptr, nullptr, nullptr, nullptr, nullptr);
}